// Round 13
// baseline (372.559 us; speedup 1.0000x reference)
//
#include <hip/hip_runtime.h>
#include <hip/hip_bf16.h>
#include <hip/hip_fp16.h>

typedef __attribute__((ext_vector_type(8))) short short8;
typedef __attribute__((ext_vector_type(4))) short short4v;
typedef __attribute__((ext_vector_type(8))) _Float16 f16x8;
typedef __attribute__((ext_vector_type(4))) _Float16 f16x4;
typedef __attribute__((ext_vector_type(4))) float f32x4;

static constexpr int TT   = 500;
static constexpr int NIN  = 128;
static constexpr int NH1  = 512;
static constexpr int NH2  = 256;
static constexpr float LO_SCALE = 4096.0f;        // 2^12
static constexpr float LO_INV   = 2.44140625e-4f; // 2^-12
static constexpr float BETA1 = 0.8187307530779818f;  // exp(-1/5)
static constexpr float BETA2 = 0.9048374180359595f;  // exp(-1/10)

__device__ __forceinline__ unsigned short f2h_bits(float x) {
    _Float16 h = (_Float16)x;
    unsigned short u;
    __builtin_memcpy(&u, &h, 2);
    return u;
}
__device__ __forceinline__ float h2f(unsigned short u) {
    _Float16 h;
    __builtin_memcpy(&h, &u, 2);
    return (float)h;
}

// Split f32 weights into 2 f16 components: w = hi + lo*2^-12 (residual ~|w|*2^-23).
// Also zeroes the two atomic spike counters (deterministic each launch).
__global__ __launch_bounds__(256) void prep_weights(
    const float* __restrict__ W1, const float* __restrict__ W2,
    unsigned short* __restrict__ w1s,   // [2][512*128] f16 bits
    unsigned short* __restrict__ w2s,   // [2][256*512]
    unsigned int* __restrict__ cnt1, unsigned int* __restrict__ cnt2)
{
    int idx = blockIdx.x * 256 + threadIdx.x;
    if (idx == 0) { cnt1[0] = 0u; cnt2[0] = 0u; }
    const int n1 = NH1 * NIN;   // 65536
    const int n2 = NH2 * NH1;   // 131072
    if (idx < n1) {
        float w = W1[idx];
        unsigned short hi = f2h_bits(w);
        float r = (w - h2f(hi)) * LO_SCALE;
        unsigned short lo = f2h_bits(r);
        w1s[idx] = hi; w1s[n1 + idx] = lo;
    }
    if (idx < n2) {
        float w = W2[idx];
        unsigned short hi = f2h_bits(w);
        float r = (w - h2f(hi)) * LO_SCALE;
        unsigned short lo = f2h_bits(r);
        w2s[idx] = hi; w2s[n2 + idx] = lo;
    }
}

// Pack f32 spikes (exact 0/1) into bits, element order preserved.
// spbits row (t*256+b) holds 128 bits (16B) over the input dim.
__global__ __launch_bounds__(256) void pack_spikes(
    const float* __restrict__ sp, unsigned long long* __restrict__ bits)
{
    int i = blockIdx.x * 256 + threadIdx.x;   // 16,384,000 threads
    bool b = sp[i] != 0.0f;
    unsigned long long m = __ballot(b);
    if ((threadIdx.x & 63) == 0) bits[i >> 6] = m;
}

// FUSED layer 1: gemm1 (bit-A x W1-splits) + LIF scan + spike bit-pack.
// Block = (b-group of 4) x (h-tile of 64); W1 slice (32KB) LDS-resident.
// Loop 32 tiles of 16 t: MFMA 64rows(16t x 4b) x 64cols -> LDS tile ->
// scan 16 t-steps (wave=b, lane=h; ballot -> spkb word). cur1 never global.
__global__ __launch_bounds__(256) void fused1(
    const unsigned char* __restrict__ Ab,     // spbits [128000*16]
    const unsigned short* __restrict__ Bs,    // w1s [2][512*128]
    const float* __restrict__ bias,           // b1
    unsigned long long* __restrict__ spkb,    // [128000][8]
    float* __restrict__ s1sum,                // [256*512]
    unsigned int* __restrict__ cnt_g)
{
    __shared__ __align__(16) unsigned short Wl[2 * 64 * 128];  // 32 KB
    __shared__ __align__(16) float tile[64 * 66];              // 16.9 KB
    __shared__ __align__(16) unsigned short lut4[64];          // 128 B

    const int tid = threadIdx.x;
    const int bg  = blockIdx.x;    // 0..63
    const int ht  = blockIdx.y;    // 0..7
    const int h0  = ht * 64;

    if (tid < 16) {
        short4v e;
#pragma unroll
        for (int i = 0; i < 4; ++i)
            e[i] = ((tid >> i) & 1) ? (short)0x3C00 : (short)0;
        *reinterpret_cast<short4v*>(&lut4[tid * 4]) = e;
    }
    // stage W1 slice, swizzled: unit u of col stored at u^(col&7)
#pragma unroll
    for (int it = 0; it < 8; ++it) {
        int uidx = tid + it * 256;               // 2048 units
        int s = uidx >> 10, rem = uidx & 1023;
        int col = rem >> 4, u = rem & 15;
        short8 v = *reinterpret_cast<const short8*>(
            Bs + s * 65536 + (h0 + col) * 128 + u * 8);
        *reinterpret_cast<short8*>(
            &Wl[(s * 64 + col) * 128 + (u ^ (col & 7)) * 8]) = v;
    }
    __syncthreads();

    const int w = tid >> 6, lane = tid & 63, lr = lane & 15, lk = lane >> 4;
    const int wr = w >> 1, wc = w & 1;

    float bcol[2];
#pragma unroll
    for (int cb = 0; cb < 2; ++cb) bcol[cb] = bias[h0 + wc * 32 + cb * 16 + lr];

    // scan identity: wave = local b, lane = local h
    const int sb = tid >> 6;
    const int sh = tid & 63;
    float mem = 0.f, sv = 0.f;
    int cnt = 0;

    for (int j = 0; j < 32; ++j) {
        f32x4 aH[2][2], aL[2][2];
#pragma unroll
        for (int a = 0; a < 2; ++a)
#pragma unroll
            for (int b = 0; b < 2; ++b) {
                aH[a][b] = (f32x4){0.f, 0.f, 0.f, 0.f};
                aL[a][b] = (f32x4){0.f, 0.f, 0.f, 0.f};
            }
#pragma unroll
        for (int ks = 0; ks < 4; ++ks) {
            f16x8 af[2];
#pragma unroll
            for (int rb = 0; rb < 2; ++rb) {
                int row = wr * 32 + rb * 16 + lr;
                int t = j * 16 + (row >> 2); if (t > 499) t = 499;
                int gr = t * 256 + bg * 4 + (row & 3);
                unsigned int by = Ab[(size_t)gr * 16 + ks * 4 + lk];
                f16x4 lo = *reinterpret_cast<const f16x4*>(&lut4[(by & 15u) * 4]);
                f16x4 hi = *reinterpret_cast<const f16x4*>(&lut4[((by >> 4) & 15u) * 4]);
                af[rb] = __builtin_shufflevector(lo, hi, 0, 1, 2, 3, 4, 5, 6, 7);
            }
#pragma unroll
            for (int cb = 0; cb < 2; ++cb) {
                int col = wc * 32 + cb * 16 + lr;
                int u = (ks * 4 + lk) ^ (col & 7);
                f16x8 bH = *reinterpret_cast<const f16x8*>(&Wl[col * 128 + u * 8]);
                f16x8 bL = *reinterpret_cast<const f16x8*>(&Wl[(64 + col) * 128 + u * 8]);
#pragma unroll
                for (int rb = 0; rb < 2; ++rb) {
                    aH[rb][cb] = __builtin_amdgcn_mfma_f32_16x16x32_f16(
                        af[rb], bH, aH[rb][cb], 0, 0, 0);
                    aL[rb][cb] = __builtin_amdgcn_mfma_f32_16x16x32_f16(
                        af[rb], bL, aL[rb][cb], 0, 0, 0);
                }
            }
        }
        // acc -> LDS tile (stride 66: <=2-way banks)
#pragma unroll
        for (int cb = 0; cb < 2; ++cb) {
            int col = wc * 32 + cb * 16 + lr;
#pragma unroll
            for (int rb = 0; rb < 2; ++rb) {
                int rbase = wr * 32 + rb * 16 + lk * 4;
#pragma unroll
                for (int jj = 0; jj < 4; ++jj)
                    tile[(rbase + jj) * 66 + col] =
                        fmaf(aL[rb][cb][jj], LO_INV, aH[rb][cb][jj]) + bcol[cb];
            }
        }
        __syncthreads();

        // scan 16 t-steps from LDS
        float cv[16];
#pragma unroll
        for (int tl = 0; tl < 16; ++tl)
            cv[tl] = tile[(tl * 4 + sb) * 66 + sh];
#pragma unroll
        for (int tl = 0; tl < 16; ++tl) {
            int t = j * 16 + tl;
            if (t < 500) {                       // wave-uniform
                mem = BETA1 * mem + cv[tl] - sv;
                bool spk = mem > 1.f;
                sv = spk ? 1.f : 0.f;
                cnt += (int)spk;
                unsigned long long B = __ballot(spk);
                if (sh == 0)
                    spkb[(size_t)(t * 256 + bg * 4 + sb) * 8 + ht] = B;
            }
        }
        __syncthreads();
    }

    s1sum[(bg * 4 + sb) * 512 + h0 + sh] = (float)cnt;
    int rc = cnt;
#pragma unroll
    for (int off = 32; off > 0; off >>= 1) rc += __shfl_down(rc, off);
    if (sh == 0) atomicAdd(cnt_g, (unsigned int)rc);
}

// FUSED layer 2: gemm2 (spike-bit A x W2-splits) + LIF scan (msum, count).
// Block = (b-group of 4) x (h2-tile of 32); W2 slice (64KB) LDS-resident.
// 32 tiles of 16 t: MFMA 64rows x 32cols -> LDS -> scan. cur2 never global.
__global__ __launch_bounds__(256) void fused2(
    const unsigned char* __restrict__ Ab,     // spkb bytes [128000*64]
    const unsigned short* __restrict__ Bs,    // w2s [2][256*512]
    const float* __restrict__ bias,           // b2
    float* __restrict__ msum,                 // [256*256]
    unsigned int* __restrict__ cnt_g)
{
    __shared__ __align__(16) unsigned short Wl[2 * 32 * 512];  // 64 KB
    __shared__ __align__(16) float tile[64 * 34];              // 8.7 KB
    __shared__ __align__(16) unsigned short lut4[64];

    const int tid = threadIdx.x;
    const int bg  = blockIdx.x;    // 0..63
    const int h2t = blockIdx.y;    // 0..7
    const int h0  = h2t * 32;

    if (tid < 16) {
        short4v e;
#pragma unroll
        for (int i = 0; i < 4; ++i)
            e[i] = ((tid >> i) & 1) ? (short)0x3C00 : (short)0;
        *reinterpret_cast<short4v*>(&lut4[tid * 4]) = e;
    }
#pragma unroll
    for (int it = 0; it < 16; ++it) {
        int uidx = tid + it * 256;               // 4096 units
        int s = uidx >> 11, rem = uidx & 2047;
        int col = rem >> 6, u = rem & 63;
        short8 v = *reinterpret_cast<const short8*>(
            Bs + s * 131072 + (h0 + col) * 512 + u * 8);
        *reinterpret_cast<short8*>(
            &Wl[(s * 32 + col) * 512 + (u ^ (col & 7)) * 8]) = v;
    }
    __syncthreads();

    const int w = tid >> 6, lane = tid & 63, lr = lane & 15, lk = lane >> 4;
    const int wr = w >> 1, wc = w & 1;

    float bcol = bias[h0 + wc * 16 + lr];

    // scan identity: tid<128: sb = tid>>5 (local b), sh = tid&31 (local h2)
    const int sb = tid >> 5;
    const int sh = tid & 31;
    float mem = 0.f, sv = 0.f, ms = 0.f;
    int cnt = 0;

    for (int j = 0; j < 32; ++j) {
        f32x4 aH[2], aL[2];
#pragma unroll
        for (int a = 0; a < 2; ++a) {
            aH[a] = (f32x4){0.f, 0.f, 0.f, 0.f};
            aL[a] = (f32x4){0.f, 0.f, 0.f, 0.f};
        }
#pragma unroll
        for (int ks = 0; ks < 16; ++ks) {
            f16x8 af[2];
#pragma unroll
            for (int rb = 0; rb < 2; ++rb) {
                int row = wr * 32 + rb * 16 + lr;
                int t = j * 16 + (row >> 2); if (t > 499) t = 499;
                int gr = t * 256 + bg * 4 + (row & 3);
                unsigned int by = Ab[(size_t)gr * 64 + ks * 4 + lk];
                f16x4 lo = *reinterpret_cast<const f16x4*>(&lut4[(by & 15u) * 4]);
                f16x4 hi = *reinterpret_cast<const f16x4*>(&lut4[((by >> 4) & 15u) * 4]);
                af[rb] = __builtin_shufflevector(lo, hi, 0, 1, 2, 3, 4, 5, 6, 7);
            }
            int col = wc * 16 + lr;
            int u = (ks * 4 + lk) ^ (col & 7);
            f16x8 bH = *reinterpret_cast<const f16x8*>(&Wl[col * 512 + u * 8]);
            f16x8 bL = *reinterpret_cast<const f16x8*>(&Wl[(32 + col) * 512 + u * 8]);
#pragma unroll
            for (int rb = 0; rb < 2; ++rb) {
                aH[rb] = __builtin_amdgcn_mfma_f32_16x16x32_f16(
                    af[rb], bH, aH[rb], 0, 0, 0);
                aL[rb] = __builtin_amdgcn_mfma_f32_16x16x32_f16(
                    af[rb], bL, aL[rb], 0, 0, 0);
            }
        }
        {
            int col = wc * 16 + lr;
#pragma unroll
            for (int rb = 0; rb < 2; ++rb) {
                int rbase = wr * 32 + rb * 16 + lk * 4;
#pragma unroll
                for (int jj = 0; jj < 4; ++jj)
                    tile[(rbase + jj) * 34 + col] =
                        fmaf(aL[rb][jj], LO_INV, aH[rb][jj]) + bcol;
            }
        }
        __syncthreads();

        if (tid < 128) {
            float cv[16];
#pragma unroll
            for (int tl = 0; tl < 16; ++tl)
                cv[tl] = tile[(tl * 4 + sb) * 34 + sh];
#pragma unroll
            for (int tl = 0; tl < 16; ++tl) {
                int t = j * 16 + tl;
                if (t < 500) {
                    mem = BETA2 * mem + cv[tl] - sv;
                    ms += mem;
                    bool spk = mem > 1.f;
                    sv = spk ? 1.f : 0.f;
                    cnt += (int)spk;
                }
            }
        }
        __syncthreads();
    }

    if (tid < 128) {
        msum[(bg * 4 + sb) * 256 + h0 + sh] = ms;
        int rc = cnt;
#pragma unroll
        for (int off = 32; off > 0; off >>= 1) rc += __shfl_down(rc, off);
        if ((tid & 63) == 0) atomicAdd(cnt_g, (unsigned int)rc);
    }
}

// out[b,o] = (msum[b,:]/T)@Wr[o,:] + br[o] + (s1sum[b,:]/T)@Ws[o,:] + bs[o]
__global__ __launch_bounds__(256) void readout(
    const float* __restrict__ msum, const float* __restrict__ s1sum,
    const float* __restrict__ Wr, const float* __restrict__ br,
    const float* __restrict__ Ws, const float* __restrict__ bs,
    const unsigned int* __restrict__ cnt1, const unsigned int* __restrict__ cnt2,
    float* __restrict__ out)
{
    __shared__ float r0[256], r1[256];
    int b = blockIdx.x, t = threadIdx.x;
    const float inv_t = 1.0f / 500.0f;
    float m  = msum[b * 256 + t] * inv_t;
    float p0 = m * Wr[t];
    float p1 = m * Wr[256 + t];
    float sa = s1sum[b * 512 + t] * inv_t;
    float sb = s1sum[b * 512 + 256 + t] * inv_t;
    p0 += sa * Ws[t]       + sb * Ws[256 + t];
    p1 += sa * Ws[512 + t] + sb * Ws[768 + t];
    r0[t] = p0; r1[t] = p1;
    __syncthreads();
    for (int st = 128; st > 0; st >>= 1) {
        if (t < st) { r0[t] += r0[t + st]; r1[t] += r1[t + st]; }
        __syncthreads();
    }
    if (t == 0) {
        out[b * 2 + 0] = r0[0] + br[0] + bs[0];
        out[b * 2 + 1] = r1[0] + br[1] + bs[1];
        if (b == 0) {
            out[512] = (float)cnt1[0] * (1.0f / 65536000.0f);
            out[513] = (float)cnt2[0] * (1.0f / 32768000.0f);
        }
    }
}

extern "C" void kernel_launch(void* const* d_in, const int* in_sizes, int n_in,
                              void* d_out, int out_size, void* d_ws, size_t ws_size,
                              hipStream_t stream) {
    const float* spikes = (const float*)d_in[0];
    const float* W1 = (const float*)d_in[1];
    const float* b1 = (const float*)d_in[2];
    const float* W2 = (const float*)d_in[3];
    const float* b2 = (const float*)d_in[4];
    const float* Wr = (const float*)d_in[5];
    const float* br = (const float*)d_in[6];
    const float* Ws = (const float*)d_in[7];
    const float* bs = (const float*)d_in[8];
    float* out = (float*)d_out;

    char* wsb = (char*)d_ws;
    size_t o = 0;
    unsigned short* w1s = (unsigned short*)(wsb + o); o += (size_t)2 * 65536 * 2;        // 256 KB
    unsigned short* w2s = (unsigned short*)(wsb + o); o += (size_t)2 * 131072 * 2;       // 512 KB
    unsigned long long* spbits = (unsigned long long*)(wsb + o); o += (size_t)256000 * 8;  // 2 MB
    unsigned long long* spkb   = (unsigned long long*)(wsb + o); o += (size_t)1024000 * 8; // 8 MB
    float* s1sum = (float*)(wsb + o); o += 524288;
    float* msum  = (float*)(wsb + o); o += 262144;
    unsigned int* cnt1 = (unsigned int*)(wsb + o); o += 256;
    unsigned int* cnt2 = (unsigned int*)(wsb + o); o += 256;

    prep_weights<<<512, 256, 0, stream>>>(W1, W2, w1s, w2s, cnt1, cnt2);
    pack_spikes<<<64000, 256, 0, stream>>>(spikes, spbits);

    fused1<<<dim3(64, 8), 256, 0, stream>>>(
        (const unsigned char*)spbits, w1s, b1, spkb, s1sum, cnt1);
    fused2<<<dim3(64, 8), 256, 0, stream>>>(
        (const unsigned char*)spkb, w2s, b2, msum, cnt2);

    readout<<<256, 256, 0, stream>>>(msum, s1sum, Wr, br, Ws, bs, cnt1, cnt2, out);
}

// Round 14
// 261.482 us; speedup vs baseline: 1.4248x; 1.4248x over previous
//
#include <hip/hip_runtime.h>
#include <hip/hip_bf16.h>
#include <hip/hip_fp16.h>

typedef __attribute__((ext_vector_type(8))) short short8;
typedef __attribute__((ext_vector_type(4))) short short4v;
typedef __attribute__((ext_vector_type(8))) _Float16 f16x8;
typedef __attribute__((ext_vector_type(4))) _Float16 f16x4;
typedef __attribute__((ext_vector_type(4))) float f32x4;

static constexpr int NIN  = 128;
static constexpr int NH1  = 512;
static constexpr int NH2  = 256;
static constexpr float LO_SCALE = 4096.0f;        // 2^12
static constexpr float LO_INV   = 2.44140625e-4f; // 2^-12
static constexpr float BETA1 = 0.8187307530779818f;  // exp(-1/5)
static constexpr float BETA2 = 0.9048374180359595f;  // exp(-1/10)

__device__ __forceinline__ unsigned short f2h_bits(float x) {
    _Float16 h = (_Float16)x;
    unsigned short u;
    __builtin_memcpy(&u, &h, 2);
    return u;
}
__device__ __forceinline__ float h2f(unsigned short u) {
    _Float16 h;
    __builtin_memcpy(&h, &u, 2);
    return (float)h;
}

__device__ __forceinline__ void gload16(const unsigned short* g, unsigned short* l) {
    __builtin_amdgcn_global_load_lds(
        (const __attribute__((address_space(1))) unsigned int*)(g),
        (__attribute__((address_space(3))) unsigned int*)(l),
        16, 0, 0);
}

// Split f32 weights into 2 f16 components: w = hi + lo*2^-12 (residual ~|w|*2^-23).
// Also zeroes the two atomic spike counters (deterministic each launch).
__global__ __launch_bounds__(256) void prep_weights(
    const float* __restrict__ W1, const float* __restrict__ W2,
    unsigned short* __restrict__ w1s,   // [2][512*128] f16 bits
    unsigned short* __restrict__ w2s,   // [2][256*512]
    unsigned int* __restrict__ cnt1, unsigned int* __restrict__ cnt2)
{
    int idx = blockIdx.x * 256 + threadIdx.x;
    if (idx == 0) { cnt1[0] = 0u; cnt2[0] = 0u; }
    const int n1 = NH1 * NIN;   // 65536
    const int n2 = NH2 * NH1;   // 131072
    if (idx < n1) {
        float w = W1[idx];
        unsigned short hi = f2h_bits(w);
        float r = (w - h2f(hi)) * LO_SCALE;
        unsigned short lo = f2h_bits(r);
        w1s[idx] = hi; w1s[n1 + idx] = lo;
    }
    if (idx < n2) {
        float w = W2[idx];
        unsigned short hi = f2h_bits(w);
        float r = (w - h2f(hi)) * LO_SCALE;
        unsigned short lo = f2h_bits(r);
        w2s[idx] = hi; w2s[n2 + idx] = lo;
    }
}

// Pack f32 spikes (exact 0/1) into bits, element order preserved.
__global__ __launch_bounds__(256) void pack_spikes(
    const float* __restrict__ sp, unsigned long long* __restrict__ bits)
{
    int i = blockIdx.x * 256 + threadIdx.x;   // 16,384,000 threads
    bool b = sp[i] != 0.0f;
    unsigned long long m = __ballot(b);
    if ((threadIdx.x & 63) == 0) bits[i >> 6] = m;
}

__device__ __forceinline__ void load_abytes(
    const unsigned char* __restrict__ Ab, int j, int bg, int wr, int lr, int lk,
    unsigned int a[2][4])
{
#pragma unroll
    for (int rb = 0; rb < 2; ++rb) {
        int row = wr * 32 + rb * 16 + lr;
        int t = j * 16 + (row >> 2); if (t > 499) t = 499;
        int gr = t * 256 + bg * 4 + (row & 3);
#pragma unroll
        for (int ks = 0; ks < 4; ++ks)
            a[rb][ks] = Ab[(size_t)gr * 16 + ks * 4 + lk];
    }
}

// FUSED layer 1: gemm1 (bit-A x W1 f16-splits) + LIF scan + spike bit-pack.
// Block = (b-group of 4) x (h-tile of 64); K=128 is small enough that each
// wave's ENTIRE B panel (2cb x 4ks x 2spl = 16 f16x8) lives in REGISTERS,
// loaded once from global (w1s is 256KB, L2-hot, shared by all blocks):
// no LDS B-reads, no W staging, no K-loop barriers. Per j-tile (16 t-steps):
// prefetch A bytes (j+1) -> LUT-expand -> 32 MFMA -> acc->tile(LDS) ->
// barrier -> in-LDS scan (wave=b, lane=h, ballot -> spkb) -> barrier.
// cur1 NEVER touches global memory (saves ~260MB of L3 round-trip).
__global__ __launch_bounds__(256) void fused1(
    const unsigned char* __restrict__ Ab,     // spbits [128000*16]
    const unsigned short* __restrict__ w1s,   // [2][512*128]
    const float* __restrict__ bias,           // b1
    unsigned long long* __restrict__ spkb,    // [128000][8]
    float* __restrict__ s1sum,                // [256*512]
    unsigned int* __restrict__ cnt_g)
{
    __shared__ __align__(16) float tile[64 * 66];        // 16.9 KB
    __shared__ __align__(16) unsigned short lut4[64];    // 128 B

    const int tid = threadIdx.x;
    const int bg  = blockIdx.x;    // 0..63
    const int ht  = blockIdx.y;    // 0..7
    const int h0  = ht * 64;

    if (tid < 16) {
        short4v e;
#pragma unroll
        for (int i = 0; i < 4; ++i)
            e[i] = ((tid >> i) & 1) ? (short)0x3C00 : (short)0;
        *reinterpret_cast<short4v*>(&lut4[tid * 4]) = e;
    }

    const int w = tid >> 6, lane = tid & 63, lr = lane & 15, lk = lane >> 4;
    const int wr = w >> 1, wc = w & 1;

    // B panel in registers: 16 f16x8 frags (64 VGPRs), loaded once from L2
    f16x8 bH[2][4], bL[2][4];
#pragma unroll
    for (int cb = 0; cb < 2; ++cb)
#pragma unroll
        for (int ks = 0; ks < 4; ++ks) {
            int col = h0 + wc * 32 + cb * 16 + lr;
            bH[cb][ks] = *reinterpret_cast<const f16x8*>(
                w1s + col * 128 + ks * 32 + lk * 8);
            bL[cb][ks] = *reinterpret_cast<const f16x8*>(
                w1s + 65536 + col * 128 + ks * 32 + lk * 8);
        }
    float bcol[2];
#pragma unroll
    for (int cb = 0; cb < 2; ++cb) bcol[cb] = bias[h0 + wc * 32 + cb * 16 + lr];

    const int sb = tid >> 6;      // scan: wave = local batch
    const int sh = tid & 63;      // lane = local hidden unit
    float mem = 0.f, sv = 0.f;
    int cnt = 0;

    unsigned int a_cur[2][4], a_nxt[2][4];
    load_abytes(Ab, 0, bg, wr, lr, lk, a_cur);
    __syncthreads();   // LUT ready

    for (int j = 0; j < 32; ++j) {
        if (j < 31) load_abytes(Ab, j + 1, bg, wr, lr, lk, a_nxt);

        f32x4 aH[2][2], aL[2][2];
#pragma unroll
        for (int a = 0; a < 2; ++a)
#pragma unroll
            for (int b = 0; b < 2; ++b) {
                aH[a][b] = (f32x4){0.f, 0.f, 0.f, 0.f};
                aL[a][b] = (f32x4){0.f, 0.f, 0.f, 0.f};
            }
#pragma unroll
        for (int ks = 0; ks < 4; ++ks) {
            f16x8 af[2];
#pragma unroll
            for (int rb = 0; rb < 2; ++rb) {
                unsigned int by = a_cur[rb][ks];
                f16x4 lo = *reinterpret_cast<const f16x4*>(&lut4[(by & 15u) * 4]);
                f16x4 hi = *reinterpret_cast<const f16x4*>(&lut4[((by >> 4) & 15u) * 4]);
                af[rb] = __builtin_shufflevector(lo, hi, 0, 1, 2, 3, 4, 5, 6, 7);
            }
#pragma unroll
            for (int cb = 0; cb < 2; ++cb)
#pragma unroll
                for (int rb = 0; rb < 2; ++rb) {
                    aH[rb][cb] = __builtin_amdgcn_mfma_f32_16x16x32_f16(
                        af[rb], bH[cb][ks], aH[rb][cb], 0, 0, 0);
                    aL[rb][cb] = __builtin_amdgcn_mfma_f32_16x16x32_f16(
                        af[rb], bL[cb][ks], aL[rb][cb], 0, 0, 0);
                }
        }
        // acc -> LDS tile (stride 66 floats: 2-way banks max)
#pragma unroll
        for (int cb = 0; cb < 2; ++cb) {
            int col = wc * 32 + cb * 16 + lr;
#pragma unroll
            for (int rb = 0; rb < 2; ++rb) {
                int rbase = wr * 32 + rb * 16 + lk * 4;
#pragma unroll
                for (int jj = 0; jj < 4; ++jj)
                    tile[(rbase + jj) * 66 + col] =
                        fmaf(aL[rb][cb][jj], LO_INV, aH[rb][cb][jj]) + bcol[cb];
            }
        }
        __syncthreads();

        // in-LDS scan of 16 t-steps (row = t_local*4 + b_local)
        float cv[16];
#pragma unroll
        for (int tl = 0; tl < 16; ++tl)
            cv[tl] = tile[(tl * 4 + sb) * 66 + sh];
#pragma unroll
        for (int tl = 0; tl < 16; ++tl) {
            int t = j * 16 + tl;
            if (t < 500) {                        // wave-uniform
                mem = BETA1 * mem + cv[tl] - sv;
                bool spk = mem > 1.f;
                sv = spk ? 1.f : 0.f;
                cnt += (int)spk;
                unsigned long long B = __ballot(spk);
                if (sh == 0)
                    spkb[(size_t)(t * 256 + bg * 4 + sb) * 8 + ht] = B;
            }
        }
        __syncthreads();

        if (j < 31) {
#pragma unroll
            for (int rb = 0; rb < 2; ++rb)
#pragma unroll
                for (int ks = 0; ks < 4; ++ks) a_cur[rb][ks] = a_nxt[rb][ks];
        }
    }

    s1sum[(bg * 4 + sb) * 512 + h0 + sh] = (float)cnt;
    int rc = cnt;
#pragma unroll
    for (int off = 32; off > 0; off >>= 1) rc += __shfl_down(rc, off);
    if (sh == 0) atomicAdd(cnt_g, (unsigned int)rc);
}

// Unified bit-A GEMM (R12, known-good): C = bits(A) * (Bhi + 2^-12*Blo)^T + bias
// Tri-buffered LDS, single barrier per K-step, counted vmcnt(8); nibble LUT.
template<int N, int K>
__global__ __launch_bounds__(256) void gemm_bits(
    const unsigned char* __restrict__ Ab,    // [M][K/8]
    const unsigned short* __restrict__ Bs,   // [2][N*K] f16 bits
    const float* __restrict__ bias,
    float* __restrict__ C,
    int M)
{
    constexpr int NK = N * K;
    constexpr int nk = K / 32;
    constexpr int kb = K / 8;

    __shared__ __align__(16) unsigned short Bsh[3][8192];   // 48 KB
    __shared__ __align__(16) unsigned short lut4[64];

    const int tid  = threadIdx.x;
    const int w    = tid >> 6;
    const int lane = tid & 63;
    const int lr   = lane & 15;
    const int lk   = lane >> 4;
    const int wr   = w >> 1;
    const int wc   = w & 1;

    if (tid < 16) {
        short4v e;
#pragma unroll
        for (int i = 0; i < 4; ++i)
            e[i] = ((tid >> i) & 1) ? (short)0x3C00 : (short)0;
        *reinterpret_cast<short4v*>(&lut4[tid * 4]) = e;
    }
    asm volatile("s_waitcnt lgkmcnt(0)" ::: "memory");

    const int m0 = blockIdx.x * 128;
    const int n0 = blockIdx.y * 128;
    const int ulog = ((lane & 3) ^ ((lane >> 3) & 3)) * 8;

    int gBoff[4], lBoff[4];
#pragma unroll
    for (int j = 0; j < 4; ++j) {
        int i = w * 4 + j;
        int s = i >> 3, blk = i & 7;
        int row = blk * 16 + (lane >> 2);
        gBoff[j] = s * NK + (n0 + row) * K + ulog;
        lBoff[j] = s * 4096 + blk * 512;
    }
    const unsigned char* aptr[4];
#pragma unroll
    for (int rb = 0; rb < 4; ++rb)
        aptr[rb] = Ab + (size_t)(m0 + wr * 64 + rb * 16 + lr) * kb + lk;

    f32x4 accH[4][4], accL[4][4];
#pragma unroll
    for (int i = 0; i < 4; ++i)
#pragma unroll
        for (int j = 0; j < 4; ++j) {
            accH[i][j] = (f32x4){0.f, 0.f, 0.f, 0.f};
            accL[i][j] = (f32x4){0.f, 0.f, 0.f, 0.f};
        }

    unsigned int ab[3][4];
#pragma unroll
    for (int p = 0; p < 2; ++p) {
#pragma unroll
        for (int j = 0; j < 4; ++j)
            gload16(Bs + gBoff[j] + p * 32, &Bsh[p][lBoff[j]]);
#pragma unroll
        for (int rb = 0; rb < 4; ++rb)
            ab[p][rb] = aptr[rb][p * 4];
    }

#pragma unroll
    for (int ks = 0; ks < nk; ++ks) {
        if (ks + 1 < nk) {
            asm volatile("s_waitcnt vmcnt(8)" ::: "memory");
        } else {
            asm volatile("s_waitcnt vmcnt(0)" ::: "memory");
        }
        __builtin_amdgcn_s_barrier();
        __builtin_amdgcn_sched_barrier(0);

        if (ks + 2 < nk) {
#pragma unroll
            for (int j = 0; j < 4; ++j)
                gload16(Bs + gBoff[j] + (ks + 2) * 32, &Bsh[(ks + 2) % 3][lBoff[j]]);
#pragma unroll
            for (int rb = 0; rb < 4; ++rb)
                ab[(ks + 2) % 3][rb] = aptr[rb][(ks + 2) * 4];
        }
        __builtin_amdgcn_sched_barrier(0);

        f16x8 af[4];
#pragma unroll
        for (int rb = 0; rb < 4; ++rb) {
            unsigned int b = ab[ks % 3][rb];
            f16x4 lo = *reinterpret_cast<const f16x4*>(&lut4[(b & 15u) * 4]);
            f16x4 hi = *reinterpret_cast<const f16x4*>(&lut4[((b >> 4) & 15u) * 4]);
            af[rb] = __builtin_shufflevector(lo, hi, 0, 1, 2, 3, 4, 5, 6, 7);
        }

#pragma unroll
        for (int cb = 0; cb < 4; ++cb) {
            int row = wc * 64 + cb * 16 + lr;
            int u = (lk ^ ((row >> 1) & 3)) * 8;
            f16x8 bfH = *reinterpret_cast<const f16x8*>(&Bsh[ks % 3][row * 32 + u]);
            f16x8 bfL = *reinterpret_cast<const f16x8*>(&Bsh[ks % 3][4096 + row * 32 + u]);
#pragma unroll
            for (int rb = 0; rb < 4; ++rb) {
                accH[rb][cb] = __builtin_amdgcn_mfma_f32_16x16x32_f16(
                    af[rb], bfH, accH[rb][cb], 0, 0, 0);
                accL[rb][cb] = __builtin_amdgcn_mfma_f32_16x16x32_f16(
                    af[rb], bfL, accL[rb][cb], 0, 0, 0);
            }
        }
    }

#pragma unroll
    for (int cb = 0; cb < 4; ++cb) {
        int col = n0 + wc * 64 + cb * 16 + lr;
        float bv = bias[col];
#pragma unroll
        for (int rb = 0; rb < 4; ++rb) {
            int row = m0 + wr * 64 + rb * 16 + lk * 4;
#pragma unroll
            for (int j = 0; j < 4; ++j)
                C[(size_t)(row + j) * N + col] =
                    fmaf(accL[rb][cb][j], LO_INV, accH[rb][cb][j]) + bv;
        }
    }
}

// LIF scan layer 2, single pass T=500 (50 pipelined groups of 10).
__global__ __launch_bounds__(256) void scan2(
    const float* __restrict__ cur,             // [500][65536]
    float* __restrict__ msum_o,
    unsigned int* __restrict__ cnt_g)
{
    int tid = blockIdx.x * 256 + threadIdx.x;  // 65536 threads
    float mem = 0.f, sv = 0.f, ms = 0.f;
    int cnt = 0;
    const float* base = cur + tid;

    float c[10], n[10];
#pragma unroll
    for (int i = 0; i < 10; ++i) c[i] = base[(size_t)i * 65536];

    for (int g = 0; g < 50; ++g) {
        if (g < 49) {
#pragma unroll
            for (int i = 0; i < 10; ++i)
                n[i] = base[(size_t)((g + 1) * 10 + i) * 65536];
        }
#pragma unroll
        for (int i = 0; i < 10; ++i) {
            mem = BETA2 * mem + c[i] - sv;
            ms += mem;
            bool b = mem > 1.f;
            sv = b ? 1.f : 0.f;
            cnt += (int)b;
        }
#pragma unroll
        for (int i = 0; i < 10; ++i) c[i] = n[i];
    }
    msum_o[tid] = ms;
    int rc = cnt;
#pragma unroll
    for (int off = 32; off > 0; off >>= 1) rc += __shfl_down(rc, off);
    if ((threadIdx.x & 63) == 0) atomicAdd(cnt_g, (unsigned int)rc);
}

// out[b,o] = (msum[b,:]/T)@Wr[o,:] + br[o] + (s1sum[b,:]/T)@Ws[o,:] + bs[o]
__global__ __launch_bounds__(256) void readout(
    const float* __restrict__ msum, const float* __restrict__ s1sum,
    const float* __restrict__ Wr, const float* __restrict__ br,
    const float* __restrict__ Ws, const float* __restrict__ bs,
    const unsigned int* __restrict__ cnt1, const unsigned int* __restrict__ cnt2,
    float* __restrict__ out)
{
    __shared__ float r0[256], r1[256];
    int b = blockIdx.x, t = threadIdx.x;
    const float inv_t = 1.0f / 500.0f;
    float m  = msum[b * 256 + t] * inv_t;
    float p0 = m * Wr[t];
    float p1 = m * Wr[256 + t];
    float sa = s1sum[b * 512 + t] * inv_t;
    float sb = s1sum[b * 512 + 256 + t] * inv_t;
    p0 += sa * Ws[t]       + sb * Ws[256 + t];
    p1 += sa * Ws[512 + t] + sb * Ws[768 + t];
    r0[t] = p0; r1[t] = p1;
    __syncthreads();
    for (int st = 128; st > 0; st >>= 1) {
        if (t < st) { r0[t] += r0[t + st]; r1[t] += r1[t + st]; }
        __syncthreads();
    }
    if (t == 0) {
        out[b * 2 + 0] = r0[0] + br[0] + bs[0];
        out[b * 2 + 1] = r1[0] + br[1] + bs[1];
        if (b == 0) {
            out[512] = (float)cnt1[0] * (1.0f / 65536000.0f);
            out[513] = (float)cnt2[0] * (1.0f / 32768000.0f);
        }
    }
}

extern "C" void kernel_launch(void* const* d_in, const int* in_sizes, int n_in,
                              void* d_out, int out_size, void* d_ws, size_t ws_size,
                              hipStream_t stream) {
    const float* spikes = (const float*)d_in[0];
    const float* W1 = (const float*)d_in[1];
    const float* b1 = (const float*)d_in[2];
    const float* W2 = (const float*)d_in[3];
    const float* b2 = (const float*)d_in[4];
    const float* Wr = (const float*)d_in[5];
    const float* br = (const float*)d_in[6];
    const float* Ws = (const float*)d_in[7];
    const float* bs = (const float*)d_in[8];
    float* out = (float*)d_out;

    char* wsb = (char*)d_ws;
    size_t o = 0;
    unsigned short* w1s = (unsigned short*)(wsb + o); o += (size_t)2 * 65536 * 2;          // 256 KB
    unsigned short* w2s = (unsigned short*)(wsb + o); o += (size_t)2 * 131072 * 2;         // 512 KB
    unsigned long long* spbits = (unsigned long long*)(wsb + o); o += (size_t)256000 * 8;  // 2 MB
    unsigned long long* spkb   = (unsigned long long*)(wsb + o); o += (size_t)1024000 * 8; // 8 MB
    float* cur2 = (float*)(wsb + o);                  o += (size_t)500 * 65536 * 4;        // 131 MB
    float* s1sum = (float*)(wsb + o); o += 524288;
    float* msum  = (float*)(wsb + o); o += 262144;
    unsigned int* cnt1 = (unsigned int*)(wsb + o); o += 256;
    unsigned int* cnt2 = (unsigned int*)(wsb + o); o += 256;

    prep_weights<<<512, 256, 0, stream>>>(W1, W2, w1s, w2s, cnt1, cnt2);
    pack_spikes<<<64000, 256, 0, stream>>>(spikes, spbits);

    fused1<<<dim3(64, 8), 256, 0, stream>>>(
        (const unsigned char*)spbits, w1s, b1, spkb, s1sum, cnt1);

    gemm_bits<NH2, NH1><<<dim3(1000, 2), 256, 0, stream>>>(
        (const unsigned char*)spkb, w2s, b2, cur2, 128000);

    scan2<<<256, 256, 0, stream>>>(cur2, msum, cnt2);

    readout<<<256, 256, 0, stream>>>(msum, s1sum, Wr, br, Ws, bs, cnt1, cnt2, out);
}